// Round 4
// baseline (427.831 us; speedup 1.0000x reference)
//
#include <hip/hip_runtime.h>
#include <math.h>

typedef __attribute__((ext_vector_type(8))) short short8;
typedef __attribute__((ext_vector_type(4))) float f32x4;
typedef __attribute__((ext_vector_type(2))) unsigned int u32x2;

#define E_NUM 16
constexpr int CAPS[E_NUM] = {1024,512,1024,256,1024,512,128,1024,512,1024,256,512,1024,128,64,512};
constexpr int OFFS[E_NUM] = {0,1024,1536,2560,2816,3840,4352,4480,5504,6016,7040,7296,7808,8832,8960,9024};
constexpr int cdiv_(int a, int b){ return (a + b - 1) / b; }
constexpr int ilog2_(int v){ int l = 0; while ((1 << l) < v) ++l; return l; }

__device__ __forceinline__ unsigned int cvt_pk_bf16(float a, float b){
  unsigned int r;
  asm("v_cvt_pk_bf16_f32 %0, %1, %2" : "=v"(r) : "v"(a), "v"(b));
  return r;
}

typedef __attribute__((address_space(1))) const unsigned char gas_u8;
typedef __attribute__((address_space(3))) unsigned char las_u8;
__device__ __forceinline__ void gl_lds16(const void* g, void* l){
  __builtin_amdgcn_global_load_lds((gas_u8*)g, (las_u8*)l, 16, 0, 0);
}

// Counted barriers: allow N youngest VMEM (the next-next B loads) to stay in
// flight across the barrier; older gl_lds forced complete by FIFO semantics.
__device__ __forceinline__ void bar_vm4(){
  __builtin_amdgcn_sched_barrier(0);
  asm volatile("s_waitcnt vmcnt(4) lgkmcnt(0)\n\ts_barrier" ::: "memory");
  __builtin_amdgcn_sched_barrier(0);
}
__device__ __forceinline__ void bar_vm0(){
  __builtin_amdgcn_sched_barrier(0);
  asm volatile("s_waitcnt vmcnt(0) lgkmcnt(0)\n\ts_barrier" ::: "memory");
  __builtin_amdgcn_sched_barrier(0);
}

// x fp32 -> bf16 (RNE), 8 elems/thread, grid-stride
__global__ __launch_bounds__(256) void cvt_bf16_kernel(const float* __restrict__ x,
                                                       unsigned short* __restrict__ xb, int n8)
{
  int i = blockIdx.x * blockDim.x + threadIdx.x;
  const int stride = gridDim.x * blockDim.x;
  for (; i < n8; i += stride) {
    f32x4 a = *reinterpret_cast<const f32x4*>(x + (size_t)i * 8);
    f32x4 b = *reinterpret_cast<const f32x4*>(x + (size_t)i * 8 + 4);
    u32x2 lo, hi;
    lo[0] = cvt_pk_bf16(a[0], a[1]); lo[1] = cvt_pk_bf16(a[2], a[3]);
    hi[0] = cvt_pk_bf16(b[0], b[1]); hi[1] = cvt_pk_bf16(b[2], b[3]);
    *reinterpret_cast<u32x2*>(xb + (size_t)i * 8)     = lo;
    *reinterpret_cast<u32x2*>(xb + (size_t)i * 8 + 4) = hi;
  }
}

// C = A @ W^T per expert.  A: [tokens][KDIM] (bf16 via global_load_lds, or fp32 reg-staged).
// W: [E][NDIM][KDIM] fp32 (reg-staged 2-deep + cvt).  Out: bf16 h with GELU, or fp32 + bias.
// LDS rows are 32 bf16 (64 B); 16B-blocks XOR-swizzled: phys_byte = byte ^ ((row&3)<<4).
template<bool A_GLDS, bool GELU_OUT, int TM, int NDIM, int KDIM, int LOG_GN, int NWG>
__global__ __launch_bounds__(256, 8)
void expert_gemm(const void* __restrict__ Av, const float* __restrict__ W,
                 const float* __restrict__ bias, void* __restrict__ Outv)
{
  constexpr int A_SZ = TM * 32;       // shorts per A buffer
  constexpr int B_SZ = 128 * 32;      // shorts per B buffer
  constexpr int GN   = 1 << LOG_GN;
  constexpr int MFR  = TM / 32;       // A-frags per wave
  constexpr int NT   = KDIM / 32;
  static_assert(NT % 2 == 0, "unroll-2 pipeline needs even NT");
  static_assert(NWG % 8 == 0, "grid must be divisible by 8 for XCD swizzle");
  static_assert(!GELU_OUT || 2 * (A_SZ + B_SZ) >= 128 * 128, "GELU transpose needs 32KB");

  __shared__ __align__(16) unsigned short smem[2 * A_SZ + 2 * B_SZ];

  const int tid  = threadIdx.x;
  const int braw = blockIdx.x;
  const int t = (braw & 7) * (NWG / 8) + (braw >> 3);   // bijective XCD swizzle

  // ---- locate (expert, m0, n0): m-fastest within groups of GN n-panels ----
  int m0 = 0, n0 = 0, Me = 0, tok0 = 0;
  size_t wbase = 0, bbase = 0;
  {
    int acc0 = 0;
    #pragma unroll
    for (int i = 0; i < E_NUM; ++i) {
      const int mt  = cdiv_(CAPS[i], TM);
      const int lmt = ilog2_(mt);
      const int nb  = mt * (NDIM / 128);
      if (t >= acc0 && t < acc0 + nb) {
        const int loc = t - acc0;
        const int g   = loc >> (lmt + LOG_GN);
        const int rem = loc & ((mt << LOG_GN) - 1);
        m0   = (rem >> LOG_GN) * TM;
        n0   = ((g << LOG_GN) | (rem & (GN - 1))) * 128;
        Me   = CAPS[i];
        tok0 = OFFS[i];
        wbase = (size_t)i * NDIM * KDIM;
        bbase = (size_t)i * NDIM;
      }
      acc0 += nb;
    }
  }
  const float* Wb = W + wbase;

  const int lane = tid & 63;
  const int wv   = tid >> 6;
  const int sr   = tid >> 3;          // 0..31 staging row
  const int sc   = (tid & 7) * 8;     // staging byte col (0..56)
  const int spc  = sc ^ ((sr & 3) << 4);  // swizzled byte col ((row&3) invariant under +32)

  const unsigned short* Ah = (const unsigned short*)Av;
  const float*          Af = (const float*)Av;

  // --- B: global fp32 -> regs (2-deep) -> LDS bf16 ---
  auto loadB = [&](int kt, f32x4 (&rb)[4]) {
    const int k0 = kt * 32;
    #pragma unroll
    for (int i = 0; i < 4; ++i)
      rb[i] = *reinterpret_cast<const f32x4*>(Wb + (size_t)(n0 + sr + 32 * i) * KDIM + k0 + (sc >> 1));
  };
  auto writeB = [&](int buf, f32x4 (&rb)[4]) {
    char* bb = (char*)(smem + 2 * A_SZ + buf * B_SZ);
    #pragma unroll
    for (int i = 0; i < 4; ++i) {
      u32x2 p;
      p[0] = cvt_pk_bf16(rb[i][0], rb[i][1]);
      p[1] = cvt_pk_bf16(rb[i][2], rb[i][3]);
      *reinterpret_cast<u32x2*>(bb + (sr + 32 * i) * 64 + spc) = p;
    }
  };

  // --- A: bf16 global -> LDS direct (pre-swizzled source), or fp32 reg-staged ---
  auto stageA_glds = [&](int buf, int kt) {
    constexpr int AI = TM / 64;                 // gl_lds16 instrs per wave
    const unsigned short* Ag = Ah + (size_t)(tok0 + m0) * KDIM + kt * 32;
    #pragma unroll
    for (int j = 0; j < AI; ++j) {
      const int rbase = wv * (AI * 16) + j * 16;
      const int r     = rbase + (lane >> 2);
      const int gblk  = (lane & 3) ^ (r & 3);   // pre-swizzle global 16B-block
      gl_lds16((const void*)(Ag + (size_t)r * KDIM + gblk * 8),
               (void*)(smem + buf * A_SZ + rbase * 32));
    }
  };
  auto loadA_reg = [&](int kt, f32x4 (&ra)[MFR]) {
    const int k0 = kt * 32;
    #pragma unroll
    for (int i = 0; i < MFR; ++i)
      ra[i] = *reinterpret_cast<const f32x4*>(Af + (size_t)(tok0 + m0 + sr + 32 * i) * KDIM + k0 + (sc >> 1));
  };
  auto writeA_reg = [&](int buf, f32x4 (&ra)[MFR]) {
    char* ab = (char*)(smem + buf * A_SZ);
    #pragma unroll
    for (int i = 0; i < MFR; ++i) {
      u32x2 p;
      p[0] = cvt_pk_bf16(ra[i][0], ra[i][1]);
      p[1] = cvt_pk_bf16(ra[i][2], ra[i][3]);
      *reinterpret_cast<u32x2*>(ab + (sr + 32 * i) * 64 + spc) = p;
    }
  };

  // compute coords
  const int wm   = (wv >> 1) * (TM / 2);
  const int wn   = (wv & 1) * 64;
  const int lrow = lane & 15;
  const int fcs  = ((lane >> 4) << 4) ^ ((lane & 3) << 4);  // swizzled frag byte col

  f32x4 acc_[MFR][4];
  #pragma unroll
  for (int i = 0; i < MFR; ++i)
    #pragma unroll
    for (int j = 0; j < 4; ++j)
      acc_[i][j] = (f32x4){0.f, 0.f, 0.f, 0.f};

  auto mfma_step = [&](int cur) {
    const char* ab = (const char*)(smem + cur * A_SZ);
    const char* bb = (const char*)(smem + 2 * A_SZ + cur * B_SZ);
    short8 afr[MFR], bfr[4];
    #pragma unroll
    for (int f = 0; f < MFR; ++f)
      afr[f] = *reinterpret_cast<const short8*>(ab + (wm + f * 16 + lrow) * 64 + fcs);
    #pragma unroll
    for (int f = 0; f < 4; ++f)
      bfr[f] = *reinterpret_cast<const short8*>(bb + (wn + f * 16 + lrow) * 64 + fcs);
    #pragma unroll
    for (int i = 0; i < MFR; ++i)
      #pragma unroll
      for (int j = 0; j < 4; ++j)
        acc_[i][j] = __builtin_amdgcn_mfma_f32_16x16x32_bf16(afr[i], bfr[j], acc_[i][j], 0, 0, 0);
  };

  if constexpr (A_GLDS) {
    f32x4 rb0[4], rb1[4];
    // prologue: B0 + A0 staged; B1 in flight across the first barrier
    loadB(0, rb0);
    stageA_glds(0, 0);
    writeB(0, rb0);          // compiler waits rb0 only (gl_lds younger, stays in flight)
    loadB(1, rb1);
    bar_vm4();               // gl_lds(t0) complete; rb1's 4 loads may remain in flight

    // body: read buf cur; stage tile kt+1 into cur^1; issue B loads for kt+2
    auto body = [&](int kt, int cur, f32x4 (&rbW)[4], f32x4 (&rbL)[4]) {
      if (kt + 1 < NT) {
        stageA_glds(cur ^ 1, kt + 1);
        writeB(cur ^ 1, rbW);              // rbW loaded a full iteration ago
      }
      if (kt + 2 < NT) loadB(kt + 2, rbL); // overlap with MFMAs below
      mfma_step(cur);
      if (kt + 2 < NT) bar_vm4(); else bar_vm0();
    };
    for (int kt = 0; kt < NT; kt += 2) {
      body(kt,     0, rb1, rb0);
      body(kt + 1, 1, rb0, rb1);
    }
  } else {
    // fallback (x fp32 reg-staged, 1-deep, plain barriers) — only if ws too small
    f32x4 rb0[4]; f32x4 ra[MFR];
    loadB(0, rb0); loadA_reg(0, ra);
    writeB(0, rb0); writeA_reg(0, ra);
    __syncthreads();
    for (int kt = 0; kt < NT; ++kt) {
      const int cur = kt & 1;
      if (kt + 1 < NT) { loadB(kt + 1, rb0); loadA_reg(kt + 1, ra); }
      mfma_step(cur);
      if (kt + 1 < NT) { writeB(cur ^ 1, rb0); writeA_reg(cur ^ 1, ra); }
      __syncthreads();
    }
  }

  // ---- epilogue ----
  float bv[4];
  #pragma unroll
  for (int f = 0; f < 4; ++f)
    bv[f] = bias[bbase + n0 + wn + f * 16 + lrow];

  if constexpr (GELU_OUT) {
    static_assert(TM == 128, "GELU path assumes 128-row tiles");
    unsigned short* hout = smem;   // [128][128] bf16 = 32 KB
    #pragma unroll
    for (int i = 0; i < MFR; ++i) {
      const int rbase = wm + i * 16 + (lane >> 4) * 4;
      #pragma unroll
      for (int j = 0; j < 4; ++j) {
        #pragma unroll
        for (int jj = 0; jj < 4; ++jj) {
          float xv = acc_[i][j][jj] + bv[j];
          // tanh-GELU: g = x * sigmoid(2*0.79788456*(x + 0.044715 x^3))
          float y2 = xv * (1.5957691216057308f + 0.07135481627f * xv * xv);
          float g  = xv * __builtin_amdgcn_rcpf(1.0f + __expf(-y2));
          hout[(rbase + jj) * 128 + wn + j * 16 + lrow] = (unsigned short)(cvt_pk_bf16(g, g) & 0xFFFFu);
        }
      }
    }
    __syncthreads();
    unsigned short* Oh = (unsigned short*)Outv;
    #pragma unroll
    for (int it = 0; it < 8; ++it) {
      int row  = it * 16 + (tid >> 4);
      int c    = (tid & 15) * 8;
      int grow = m0 + row;
      if (grow < Me) {
        *reinterpret_cast<short8*>(Oh + (size_t)(tok0 + grow) * NDIM + n0 + c)
          = *reinterpret_cast<const short8*>(hout + row * 128 + c);
      }
    }
  } else {
    float* Of = (float*)Outv;
    #pragma unroll
    for (int i = 0; i < MFR; ++i) {
      const int rbase = wm + i * 16 + (lane >> 4) * 4;
      #pragma unroll
      for (int jj = 0; jj < 4; ++jj) {
        int grow = m0 + rbase + jj;
        if (grow < Me) {
          #pragma unroll
          for (int j = 0; j < 4; ++j) {
            Of[(size_t)(tok0 + grow) * NDIM + n0 + wn + j * 16 + lrow] = acc_[i][j][jj] + bv[j];
          }
        }
      }
    }
  }
}

extern "C" void kernel_launch(void* const* d_in, const int* in_sizes, int n_in,
                              void* d_out, int out_size, void* d_ws, size_t ws_size,
                              hipStream_t stream)
{
  const float* x  = (const float*)d_in[0];
  const float* W1 = (const float*)d_in[1];
  const float* b1 = (const float*)d_in[2];
  const float* W2 = (const float*)d_in[3];
  const float* b2 = (const float*)d_in[4];
  float* out = (float*)d_out;

  constexpr size_t H_BYTES  = (size_t)9536 * 4096 * 2;   // h bf16
  constexpr size_t XB_BYTES = (size_t)9536 * 1024 * 2;   // x bf16
  unsigned short* h  = (unsigned short*)d_ws;
  unsigned short* xb = (unsigned short*)((char*)d_ws + H_BYTES);

  const bool use_xb = ws_size >= H_BYTES + XB_BYTES;

  if (use_xb) {
    cvt_bf16_kernel<<<2048, 256, 0, stream>>>(x, xb, 9536 * 1024 / 8);
    // GEMM1: h = gelu(x @ W1^T + b1), 128x128 tiles, GN=4
    expert_gemm<true, true, 128, 4096, 1024, 2, 75 * 32>
        <<<75 * 32, 256, 0, stream>>>((const void*)xb, W1, b1, (void*)h);
  } else {
    expert_gemm<false, true, 128, 4096, 1024, 2, 75 * 32>
        <<<75 * 32, 256, 0, stream>>>((const void*)x, W1, b1, (void*)h);
  }

  // GEMM2: out = h @ W2^T + b2, 64x128 tiles, GN=1 (2MB W2 panel per L2)
  expert_gemm<true, false, 64, 1024, 4096, 0, 149 * 8>
      <<<149 * 8, 256, 0, stream>>>((const void*)h, W2, b2, (void*)out);
}

// Round 5
// 403.541 us; speedup vs baseline: 1.0602x; 1.0602x over previous
//
#include <hip/hip_runtime.h>
#include <math.h>

typedef __attribute__((ext_vector_type(8))) short short8;
typedef __attribute__((ext_vector_type(4))) float f32x4;
typedef __attribute__((ext_vector_type(2))) unsigned int u32x2;

#define E_NUM 16
constexpr int CAPS[E_NUM] = {1024,512,1024,256,1024,512,128,1024,512,1024,256,512,1024,128,64,512};
constexpr int OFFS[E_NUM] = {0,1024,1536,2560,2816,3840,4352,4480,5504,6016,7040,7296,7808,8832,8960,9024};
constexpr int cdiv_(int a, int b){ return (a + b - 1) / b; }
constexpr int ilog2_(int v){ int l = 0; while ((1 << l) < v) ++l; return l; }

__device__ __forceinline__ unsigned int cvt_pk_bf16(float a, float b){
  unsigned int r;
  asm("v_cvt_pk_bf16_f32 %0, %1, %2" : "=v"(r) : "v"(a), "v"(b));
  return r;
}

typedef __attribute__((address_space(1))) const unsigned char gas_u8;
typedef __attribute__((address_space(3))) unsigned char las_u8;
__device__ __forceinline__ void gl_lds16(const void* g, void* l){
  __builtin_amdgcn_global_load_lds((gas_u8*)g, (las_u8*)l, 16, 0, 0);
}

// x fp32 -> bf16 (RNE), 8 elems/thread, grid-stride
__global__ __launch_bounds__(256) void cvt_bf16_kernel(const float* __restrict__ x,
                                                       unsigned short* __restrict__ xb, int n8)
{
  int i = blockIdx.x * blockDim.x + threadIdx.x;
  const int stride = gridDim.x * blockDim.x;
  for (; i < n8; i += stride) {
    f32x4 a = *reinterpret_cast<const f32x4*>(x + (size_t)i * 8);
    f32x4 b = *reinterpret_cast<const f32x4*>(x + (size_t)i * 8 + 4);
    u32x2 lo, hi;
    lo[0] = cvt_pk_bf16(a[0], a[1]); lo[1] = cvt_pk_bf16(a[2], a[3]);
    hi[0] = cvt_pk_bf16(b[0], b[1]); hi[1] = cvt_pk_bf16(b[2], b[3]);
    *reinterpret_cast<u32x2*>(xb + (size_t)i * 8)     = lo;
    *reinterpret_cast<u32x2*>(xb + (size_t)i * 8 + 4) = hi;
  }
}

// C = A @ W^T per expert.  A: [tokens][KDIM] (bf16 via global_load_lds, or fp32 reg-staged).
// W: [E][NDIM][KDIM] fp32 (reg-staged + cvt).  Out: bf16 h with GELU, or fp32 + bias
// (KS>1: split-K, fp32 atomicAdd with bias/KS per chunk; d_out must be pre-zeroed).
// LDS rows are 32 bf16 (64 B); 16B-blocks XOR-swizzled: phys_byte = byte ^ ((row&3)<<4).
template<bool A_GLDS, bool GELU_OUT, int TM, int NDIM, int KDIM, int LOG_GN, int NWG, int KS>
__global__ __launch_bounds__(256, 8)
void expert_gemm(const void* __restrict__ Av, const float* __restrict__ W,
                 const float* __restrict__ bias, void* __restrict__ Outv)
{
  constexpr int A_SZ = TM * 32;       // shorts per A buffer
  constexpr int B_SZ = 128 * 32;      // shorts per B buffer
  constexpr int GN   = 1 << LOG_GN;
  constexpr int MFR  = TM / 32;       // A-frags per wave
  constexpr int NT   = KDIM / (KS * 32);
  constexpr int NWG1 = NWG / KS;      // blocks per K-chunk
  static_assert(NWG % 8 == 0, "grid must be divisible by 8 for XCD swizzle");
  static_assert(!GELU_OUT || 2 * (A_SZ + B_SZ) >= 128 * 128, "GELU transpose needs 32KB");
  static_assert(!GELU_OUT || KS == 1, "GELU path is KS=1 only");

  __shared__ __align__(16) unsigned short smem[2 * A_SZ + 2 * B_SZ];

  const int tid  = threadIdx.x;
  const int braw = blockIdx.x;
  const int t = (braw & 7) * (NWG / 8) + (braw >> 3);   // bijective XCD swizzle

  const int kc    = t / NWG1;           // K-chunk index (chunk-major after swizzle)
  const int tt    = t % NWG1;
  const int kbase = kc * (KDIM / KS);   // element offset in K

  // ---- locate (expert, m0, n0): m-fastest within groups of GN n-panels ----
  int m0 = 0, n0 = 0, Me = 0, tok0 = 0;
  size_t wbase = 0, bbase = 0;
  {
    int acc0 = 0;
    #pragma unroll
    for (int i = 0; i < E_NUM; ++i) {
      const int mt  = cdiv_(CAPS[i], TM);
      const int lmt = ilog2_(mt);
      const int nb  = mt * (NDIM / 128);
      if (tt >= acc0 && tt < acc0 + nb) {
        const int loc = tt - acc0;
        const int g   = loc >> (lmt + LOG_GN);
        const int rem = loc & ((mt << LOG_GN) - 1);
        m0   = (rem >> LOG_GN) * TM;
        n0   = ((g << LOG_GN) | (rem & (GN - 1))) * 128;
        Me   = CAPS[i];
        tok0 = OFFS[i];
        wbase = (size_t)i * NDIM * KDIM;
        bbase = (size_t)i * NDIM;
      }
      acc0 += nb;
    }
  }
  const float* Wb = W + wbase;

  const int lane = tid & 63;
  const int wv   = tid >> 6;
  const int sr   = tid >> 3;          // 0..31 staging row
  const int sc   = (tid & 7) * 8;     // staging byte col (0..56)
  const int spc  = sc ^ ((sr & 3) << 4);  // swizzled byte col ((row&3) invariant under +32)

  const unsigned short* Ah = (const unsigned short*)Av;
  const float*          Af = (const float*)Av;

  f32x4 ra[MFR]; f32x4 rb[4];

  // --- B: global fp32 -> regs -> LDS bf16 ---
  auto loadB = [&](int kt) {
    const int k0 = kbase + kt * 32;
    #pragma unroll
    for (int i = 0; i < 4; ++i)
      rb[i] = *reinterpret_cast<const f32x4*>(Wb + (size_t)(n0 + sr + 32 * i) * KDIM + k0 + (sc >> 1));
  };
  auto writeB = [&](int buf) {
    char* bb = (char*)(smem + 2 * A_SZ + buf * B_SZ);
    #pragma unroll
    for (int i = 0; i < 4; ++i) {
      u32x2 p;
      p[0] = cvt_pk_bf16(rb[i][0], rb[i][1]);
      p[1] = cvt_pk_bf16(rb[i][2], rb[i][3]);
      *reinterpret_cast<u32x2*>(bb + (sr + 32 * i) * 64 + spc) = p;
    }
  };

  // --- A: bf16 global -> LDS direct (pre-swizzled source), or fp32 reg-staged ---
  auto stageA_glds = [&](int buf, int kt) {
    constexpr int AI = TM / 64;                 // gl_lds16 instrs per wave
    const unsigned short* Ag = Ah + (size_t)(tok0 + m0) * KDIM + kbase + kt * 32;
    #pragma unroll
    for (int j = 0; j < AI; ++j) {
      const int rbase = wv * (AI * 16) + j * 16;
      const int r     = rbase + (lane >> 2);
      const int gblk  = (lane & 3) ^ (r & 3);   // pre-swizzle global 16B-block
      gl_lds16((const void*)(Ag + (size_t)r * KDIM + gblk * 8),
               (void*)(smem + buf * A_SZ + rbase * 32));
    }
  };
  auto loadA_reg = [&](int kt) {
    const int k0 = kbase + kt * 32;
    #pragma unroll
    for (int i = 0; i < MFR; ++i)
      ra[i] = *reinterpret_cast<const f32x4*>(Af + (size_t)(tok0 + m0 + sr + 32 * i) * KDIM + k0 + (sc >> 1));
  };
  auto writeA_reg = [&](int buf) {
    char* ab = (char*)(smem + buf * A_SZ);
    #pragma unroll
    for (int i = 0; i < MFR; ++i) {
      u32x2 p;
      p[0] = cvt_pk_bf16(ra[i][0], ra[i][1]);
      p[1] = cvt_pk_bf16(ra[i][2], ra[i][3]);
      *reinterpret_cast<u32x2*>(ab + (sr + 32 * i) * 64 + spc) = p;
    }
  };

  // compute coords
  const int wm   = (wv >> 1) * (TM / 2);
  const int wn   = (wv & 1) * 64;
  const int lrow = lane & 15;
  const int fcs  = ((lane >> 4) << 4) ^ ((lane & 3) << 4);  // swizzled frag byte col

  f32x4 acc_[MFR][4];
  #pragma unroll
  for (int i = 0; i < MFR; ++i)
    #pragma unroll
    for (int j = 0; j < 4; ++j)
      acc_[i][j] = (f32x4){0.f, 0.f, 0.f, 0.f};

  auto mfma_step = [&](int cur) {
    const char* ab = (const char*)(smem + cur * A_SZ);
    const char* bb = (const char*)(smem + 2 * A_SZ + cur * B_SZ);
    short8 afr[MFR], bfr[4];
    #pragma unroll
    for (int f = 0; f < MFR; ++f)
      afr[f] = *reinterpret_cast<const short8*>(ab + (wm + f * 16 + lrow) * 64 + fcs);
    #pragma unroll
    for (int f = 0; f < 4; ++f)
      bfr[f] = *reinterpret_cast<const short8*>(bb + (wn + f * 16 + lrow) * 64 + fcs);
    #pragma unroll
    for (int i = 0; i < MFR; ++i)
      #pragma unroll
      for (int j = 0; j < 4; ++j)
        acc_[i][j] = __builtin_amdgcn_mfma_f32_16x16x32_bf16(afr[i], bfr[j], acc_[i][j], 0, 0, 0);
  };

  // ---- R3-proven 1-deep loop: plain __syncthreads(), compiler schedules waits ----
  loadB(0);
  if constexpr (A_GLDS) stageA_glds(0, 0); else loadA_reg(0);
  writeB(0);
  if constexpr (!A_GLDS) writeA_reg(0);
  __syncthreads();

  for (int kt = 0; kt < NT; ++kt) {
    const int cur = kt & 1;
    if (kt + 1 < NT) {
      loadB(kt + 1);
      if constexpr (A_GLDS) stageA_glds(cur ^ 1, kt + 1);
      else                  loadA_reg(kt + 1);
    }
    mfma_step(cur);
    if (kt + 1 < NT) {
      writeB(cur ^ 1);
      if constexpr (!A_GLDS) writeA_reg(cur ^ 1);
    }
    __syncthreads();
  }

  // ---- epilogue ----
  float bv[4];
  #pragma unroll
  for (int f = 0; f < 4; ++f)
    bv[f] = bias[bbase + n0 + wn + f * 16 + lrow];

  if constexpr (GELU_OUT) {
    static_assert(TM == 128, "GELU path assumes 128-row tiles");
    unsigned short* hout = smem;   // [128][128] bf16 = 32 KB
    #pragma unroll
    for (int i = 0; i < MFR; ++i) {
      const int rbase = wm + i * 16 + (lane >> 4) * 4;
      #pragma unroll
      for (int j = 0; j < 4; ++j) {
        #pragma unroll
        for (int jj = 0; jj < 4; ++jj) {
          float xv = acc_[i][j][jj] + bv[j];
          // tanh-GELU: g = x * sigmoid(2*0.79788456*(x + 0.044715 x^3))
          float y2 = xv * (1.5957691216057308f + 0.07135481627f * xv * xv);
          float g  = xv * __builtin_amdgcn_rcpf(1.0f + __expf(-y2));
          hout[(rbase + jj) * 128 + wn + j * 16 + lrow] = (unsigned short)(cvt_pk_bf16(g, g) & 0xFFFFu);
        }
      }
    }
    __syncthreads();
    unsigned short* Oh = (unsigned short*)Outv;
    #pragma unroll
    for (int it = 0; it < 8; ++it) {
      int row  = it * 16 + (tid >> 4);
      int c    = (tid & 15) * 8;
      int grow = m0 + row;
      if (grow < Me) {
        *reinterpret_cast<short8*>(Oh + (size_t)(tok0 + grow) * NDIM + n0 + c)
          = *reinterpret_cast<const short8*>(hout + row * 128 + c);
      }
    }
  } else {
    float* Of = (float*)Outv;
    constexpr float BS = 1.0f / (float)KS;
    #pragma unroll
    for (int i = 0; i < MFR; ++i) {
      const int rbase = wm + i * 16 + (lane >> 4) * 4;
      #pragma unroll
      for (int jj = 0; jj < 4; ++jj) {
        int grow = m0 + rbase + jj;
        if (grow < Me) {
          #pragma unroll
          for (int j = 0; j < 4; ++j) {
            float v = acc_[i][j][jj] + bv[j] * BS;
            float* p = Of + (size_t)(tok0 + grow) * NDIM + n0 + wn + j * 16 + lrow;
            if constexpr (KS > 1) unsafeAtomicAdd(p, v);
            else                  *p = v;
          }
        }
      }
    }
  }
}

extern "C" void kernel_launch(void* const* d_in, const int* in_sizes, int n_in,
                              void* d_out, int out_size, void* d_ws, size_t ws_size,
                              hipStream_t stream)
{
  const float* x  = (const float*)d_in[0];
  const float* W1 = (const float*)d_in[1];
  const float* b1 = (const float*)d_in[2];
  const float* W2 = (const float*)d_in[3];
  const float* b2 = (const float*)d_in[4];
  float* out = (float*)d_out;

  constexpr size_t H_BYTES  = (size_t)9536 * 4096 * 2;   // h bf16
  constexpr size_t XB_BYTES = (size_t)9536 * 1024 * 2;   // x bf16
  unsigned short* h  = (unsigned short*)d_ws;
  unsigned short* xb = (unsigned short*)((char*)d_ws + H_BYTES);

  const bool use_xb = ws_size >= H_BYTES + XB_BYTES;

  // zero d_out for split-K atomic accumulation (overlaps nothing; ~8 us)
  hipMemsetAsync(d_out, 0, (size_t)out_size * sizeof(float), stream);

  if (use_xb) {
    cvt_bf16_kernel<<<2048, 256, 0, stream>>>(x, xb, 9536 * 1024 / 8);
    // GEMM1: h = gelu(x @ W1^T + b1), 128x128 tiles, GN=4
    expert_gemm<true, true, 128, 4096, 1024, 2, 75 * 32, 1>
        <<<75 * 32, 256, 0, stream>>>((const void*)xb, W1, b1, (void*)h);
  } else {
    expert_gemm<false, true, 128, 4096, 1024, 2, 75 * 32, 1>
        <<<75 * 32, 256, 0, stream>>>((const void*)x, W1, b1, (void*)h);
  }

  // GEMM2: out = h @ W2^T + b2, 64x128 tiles, split-K KS=2 (NT=64/chunk),
  // atomic fp32 accumulate, bias/2 folded per chunk.
  expert_gemm<true, false, 64, 1024, 4096, 0, 2 * 149 * 8, 2>
      <<<2 * 149 * 8, 256, 0, stream>>>((const void*)h, W2, b2, (void*)out);
}

// Round 6
// 367.221 us; speedup vs baseline: 1.1650x; 1.0989x over previous
//
#include <hip/hip_runtime.h>
#include <math.h>

typedef __attribute__((ext_vector_type(8))) short short8;
typedef __attribute__((ext_vector_type(4))) float f32x4;
typedef __attribute__((ext_vector_type(2))) unsigned int u32x2;

#define E_NUM 16
constexpr int CAPS[E_NUM] = {1024,512,1024,256,1024,512,128,1024,512,1024,256,512,1024,128,64,512};
constexpr int OFFS[E_NUM] = {0,1024,1536,2560,2816,3840,4352,4480,5504,6016,7040,7296,7808,8832,8960,9024};
constexpr int cdiv_(int a, int b){ return (a + b - 1) / b; }
constexpr int ilog2_(int v){ int l = 0; while ((1 << l) < v) ++l; return l; }

__device__ __forceinline__ unsigned int cvt_pk_bf16(float a, float b){
  unsigned int r;
  asm("v_cvt_pk_bf16_f32 %0, %1, %2" : "=v"(r) : "v"(a), "v"(b));
  return r;
}

typedef __attribute__((address_space(1))) const unsigned char gas_u8;
typedef __attribute__((address_space(3))) unsigned char las_u8;
__device__ __forceinline__ void gl_lds16(const void* g, void* l){
  __builtin_amdgcn_global_load_lds((gas_u8*)g, (las_u8*)l, 16, 0, 0);
}

// x fp32 -> bf16 (RNE), 8 elems/thread, grid-stride
__global__ __launch_bounds__(256) void cvt_bf16_kernel(const float* __restrict__ x,
                                                       unsigned short* __restrict__ xb, int n8)
{
  int i = blockIdx.x * blockDim.x + threadIdx.x;
  const int stride = gridDim.x * blockDim.x;
  for (; i < n8; i += stride) {
    f32x4 a = *reinterpret_cast<const f32x4*>(x + (size_t)i * 8);
    f32x4 b = *reinterpret_cast<const f32x4*>(x + (size_t)i * 8 + 4);
    u32x2 lo, hi;
    lo[0] = cvt_pk_bf16(a[0], a[1]); lo[1] = cvt_pk_bf16(a[2], a[3]);
    hi[0] = cvt_pk_bf16(b[0], b[1]); hi[1] = cvt_pk_bf16(b[2], b[3]);
    *reinterpret_cast<u32x2*>(xb + (size_t)i * 8)     = lo;
    *reinterpret_cast<u32x2*>(xb + (size_t)i * 8 + 4) = hi;
  }
}

// C = A @ W^T per expert.  A: [tokens][KDIM] (bf16 via global_load_lds, or fp32 reg-staged).
// W: [E][NDIM][KDIM] fp32 (reg-staged + cvt).  Out: bf16 h with GELU, or fp32 + bias
// (KS>1: split-K, fp32 atomicAdd with bias/KS per chunk; d_out must be pre-zeroed).
// LDS rows are 32 bf16 (64 B); 16B-blocks XOR-swizzled on ROW BITS [3:2]:
//   phys_byte = byte ^ (((row>>2)&3)<<4)
// Bank check (bank = (row&1)*16 + 4*slot): 16 lanes reading 16 consecutive rows at one
// slot get distinct (row&1, slot^((row>>2)&3)) except l <-> l^2 => 2-way = free (m136).
template<bool A_GLDS, bool GELU_OUT, int TM, int NDIM, int KDIM, int LOG_GN, int NWG, int KS>
__global__ __launch_bounds__(256, 8)
void expert_gemm(const void* __restrict__ Av, const float* __restrict__ W,
                 const float* __restrict__ bias, void* __restrict__ Outv)
{
  constexpr int A_SZ = TM * 32;       // shorts per A buffer
  constexpr int B_SZ = 128 * 32;      // shorts per B buffer
  constexpr int GN   = 1 << LOG_GN;
  constexpr int MFR  = TM / 32;       // A-frags per wave
  constexpr int NT   = KDIM / (KS * 32);
  constexpr int NWG1 = NWG / KS;      // blocks per K-chunk
  static_assert(NWG % 8 == 0, "grid must be divisible by 8 for XCD swizzle");
  static_assert(!GELU_OUT || 2 * (A_SZ + B_SZ) >= 128 * 128, "GELU transpose needs 32KB");
  static_assert(!GELU_OUT || KS == 1, "GELU path is KS=1 only");

  __shared__ __align__(16) unsigned short smem[2 * A_SZ + 2 * B_SZ];

  const int tid  = threadIdx.x;
  const int braw = blockIdx.x;
  const int t = (braw & 7) * (NWG / 8) + (braw >> 3);   // bijective XCD swizzle

  const int kc    = t / NWG1;           // K-chunk index (chunks segregate by XCD)
  const int tt    = t % NWG1;
  const int kbase = kc * (KDIM / KS);   // element offset in K

  // ---- locate (expert, m0, n0): m-fastest within groups of GN n-panels ----
  int m0 = 0, n0 = 0, Me = 0, tok0 = 0;
  size_t wbase = 0, bbase = 0;
  {
    int acc0 = 0;
    #pragma unroll
    for (int i = 0; i < E_NUM; ++i) {
      const int mt  = cdiv_(CAPS[i], TM);
      const int lmt = ilog2_(mt);
      const int nb  = mt * (NDIM / 128);
      if (tt >= acc0 && tt < acc0 + nb) {
        const int loc = tt - acc0;
        const int g   = loc >> (lmt + LOG_GN);
        const int rem = loc & ((mt << LOG_GN) - 1);
        m0   = (rem >> LOG_GN) * TM;
        n0   = ((g << LOG_GN) | (rem & (GN - 1))) * 128;
        Me   = CAPS[i];
        tok0 = OFFS[i];
        wbase = (size_t)i * NDIM * KDIM;
        bbase = (size_t)i * NDIM;
      }
      acc0 += nb;
    }
  }
  const float* Wb = W + wbase;

  const int lane = tid & 63;
  const int wv   = tid >> 6;
  const int sr   = tid >> 3;              // 0..31 staging row
  const int sc   = (tid & 7) * 8;         // staging byte col (0..56)
  const int spc  = sc ^ (((sr >> 2) & 3) << 4);  // swizzled ((row>>2)&3 invariant under +32)

  const unsigned short* Ah = (const unsigned short*)Av;
  const float*          Af = (const float*)Av;

  f32x4 ra[MFR]; f32x4 rb[4];

  // --- B: global fp32 -> regs -> LDS bf16 ---
  auto loadB = [&](int kt) {
    const int k0 = kbase + kt * 32;
    #pragma unroll
    for (int i = 0; i < 4; ++i)
      rb[i] = *reinterpret_cast<const f32x4*>(Wb + (size_t)(n0 + sr + 32 * i) * KDIM + k0 + (sc >> 1));
  };
  auto writeB = [&](int buf) {
    char* bb = (char*)(smem + 2 * A_SZ + buf * B_SZ);
    #pragma unroll
    for (int i = 0; i < 4; ++i) {
      u32x2 p;
      p[0] = cvt_pk_bf16(rb[i][0], rb[i][1]);
      p[1] = cvt_pk_bf16(rb[i][2], rb[i][3]);
      *reinterpret_cast<u32x2*>(bb + (sr + 32 * i) * 64 + spc) = p;
    }
  };

  // --- A: bf16 global -> LDS direct (pre-swizzled source), or fp32 reg-staged ---
  auto stageA_glds = [&](int buf, int kt) {
    constexpr int AI = TM / 64;                 // gl_lds16 instrs per wave
    const unsigned short* Ag = Ah + (size_t)(tok0 + m0) * KDIM + kbase + kt * 32;
    #pragma unroll
    for (int j = 0; j < AI; ++j) {
      const int rbase = wv * (AI * 16) + j * 16;
      const int r     = rbase + (lane >> 2);
      const int gblk  = (lane & 3) ^ ((r >> 2) & 3);   // pre-swizzle global 16B-block
      gl_lds16((const void*)(Ag + (size_t)r * KDIM + gblk * 8),
               (void*)(smem + buf * A_SZ + rbase * 32));
    }
  };
  auto loadA_reg = [&](int kt) {
    const int k0 = kbase + kt * 32;
    #pragma unroll
    for (int i = 0; i < MFR; ++i)
      ra[i] = *reinterpret_cast<const f32x4*>(Af + (size_t)(tok0 + m0 + sr + 32 * i) * KDIM + k0 + (sc >> 1));
  };
  auto writeA_reg = [&](int buf) {
    char* ab = (char*)(smem + buf * A_SZ);
    #pragma unroll
    for (int i = 0; i < MFR; ++i) {
      u32x2 p;
      p[0] = cvt_pk_bf16(ra[i][0], ra[i][1]);
      p[1] = cvt_pk_bf16(ra[i][2], ra[i][3]);
      *reinterpret_cast<u32x2*>(ab + (sr + 32 * i) * 64 + spc) = p;
    }
  };

  // compute coords
  const int wm   = (wv >> 1) * (TM / 2);
  const int wn   = (wv & 1) * 64;
  const int lrow = lane & 15;
  // fragment row = base16 + lrow => (row>>2)&3 == (lane>>2)&3
  const int fcs  = ((lane >> 4) << 4) ^ (((lane >> 2) & 3) << 4);

  f32x4 acc_[MFR][4];
  #pragma unroll
  for (int i = 0; i < MFR; ++i)
    #pragma unroll
    for (int j = 0; j < 4; ++j)
      acc_[i][j] = (f32x4){0.f, 0.f, 0.f, 0.f};

  auto mfma_step = [&](int cur) {
    const char* ab = (const char*)(smem + cur * A_SZ);
    const char* bb = (const char*)(smem + 2 * A_SZ + cur * B_SZ);
    short8 afr[MFR], bfr[4];
    #pragma unroll
    for (int f = 0; f < MFR; ++f)
      afr[f] = *reinterpret_cast<const short8*>(ab + (wm + f * 16 + lrow) * 64 + fcs);
    #pragma unroll
    for (int f = 0; f < 4; ++f)
      bfr[f] = *reinterpret_cast<const short8*>(bb + (wn + f * 16 + lrow) * 64 + fcs);
    #pragma unroll
    for (int i = 0; i < MFR; ++i)
      #pragma unroll
      for (int j = 0; j < 4; ++j)
        acc_[i][j] = __builtin_amdgcn_mfma_f32_16x16x32_bf16(afr[i], bfr[j], acc_[i][j], 0, 0, 0);
  };

  // ---- 1-deep double-buffered loop (R3-proven); compiler schedules waits ----
  loadB(0);
  if constexpr (A_GLDS) stageA_glds(0, 0); else loadA_reg(0);
  writeB(0);
  if constexpr (!A_GLDS) writeA_reg(0);
  __syncthreads();

  for (int kt = 0; kt < NT; ++kt) {
    const int cur = kt & 1;
    if (kt + 1 < NT) {
      loadB(kt + 1);
      if constexpr (A_GLDS) stageA_glds(cur ^ 1, kt + 1);
      else                  loadA_reg(kt + 1);
    }
    mfma_step(cur);
    if (kt + 1 < NT) {
      writeB(cur ^ 1);
      if constexpr (!A_GLDS) writeA_reg(cur ^ 1);
    }
    __syncthreads();
  }

  // ---- epilogue ----
  float bv[4];
  #pragma unroll
  for (int f = 0; f < 4; ++f)
    bv[f] = bias[bbase + n0 + wn + f * 16 + lrow];

  if constexpr (GELU_OUT) {
    static_assert(TM == 128, "GELU path assumes 128-row tiles");
    unsigned short* hout = smem;   // [128][128] bf16 = 32 KB
    #pragma unroll
    for (int i = 0; i < MFR; ++i) {
      const int rbase = wm + i * 16 + (lane >> 4) * 4;
      #pragma unroll
      for (int j = 0; j < 4; ++j) {
        #pragma unroll
        for (int jj = 0; jj < 4; ++jj) {
          float xv = acc_[i][j][jj] + bv[j];
          // tanh-GELU: g = x * sigmoid(2*0.79788456*(x + 0.044715 x^3))
          float y2 = xv * (1.5957691216057308f + 0.07135481627f * xv * xv);
          float g  = xv * __builtin_amdgcn_rcpf(1.0f + __expf(-y2));
          hout[(rbase + jj) * 128 + wn + j * 16 + lrow] = (unsigned short)(cvt_pk_bf16(g, g) & 0xFFFFu);
        }
      }
    }
    __syncthreads();
    unsigned short* Oh = (unsigned short*)Outv;
    #pragma unroll
    for (int it = 0; it < 8; ++it) {
      int row  = it * 16 + (tid >> 4);
      int c    = (tid & 15) * 8;
      int grow = m0 + row;
      if (grow < Me) {
        *reinterpret_cast<short8*>(Oh + (size_t)(tok0 + grow) * NDIM + n0 + c)
          = *reinterpret_cast<const short8*>(hout + row * 128 + c);
      }
    }
  } else {
    float* Of = (float*)Outv;
    constexpr float BS = 1.0f / (float)KS;
    #pragma unroll
    for (int i = 0; i < MFR; ++i) {
      const int rbase = wm + i * 16 + (lane >> 4) * 4;
      #pragma unroll
      for (int jj = 0; jj < 4; ++jj) {
        int grow = m0 + rbase + jj;
        if (grow < Me) {
          #pragma unroll
          for (int j = 0; j < 4; ++j) {
            float v = acc_[i][j][jj] + bv[j] * BS;
            float* p = Of + (size_t)(tok0 + grow) * NDIM + n0 + wn + j * 16 + lrow;
            if constexpr (KS > 1) unsafeAtomicAdd(p, v);
            else                  *p = v;
          }
        }
      }
    }
  }
}

extern "C" void kernel_launch(void* const* d_in, const int* in_sizes, int n_in,
                              void* d_out, int out_size, void* d_ws, size_t ws_size,
                              hipStream_t stream)
{
  const float* x  = (const float*)d_in[0];
  const float* W1 = (const float*)d_in[1];
  const float* b1 = (const float*)d_in[2];
  const float* W2 = (const float*)d_in[3];
  const float* b2 = (const float*)d_in[4];
  float* out = (float*)d_out;

  constexpr size_t H_BYTES  = (size_t)9536 * 4096 * 2;   // h bf16
  constexpr size_t XB_BYTES = (size_t)9536 * 1024 * 2;   // x bf16
  unsigned short* h  = (unsigned short*)d_ws;
  unsigned short* xb = (unsigned short*)((char*)d_ws + H_BYTES);

  const bool use_xb = ws_size >= H_BYTES + XB_BYTES;

  // zero d_out for split-K atomic accumulation
  hipMemsetAsync(d_out, 0, (size_t)out_size * sizeof(float), stream);

  if (use_xb) {
    cvt_bf16_kernel<<<2048, 256, 0, stream>>>(x, xb, 9536 * 1024 / 8);
    // GEMM1: h = gelu(x @ W1^T + b1), 128x128 tiles, GN=4
    expert_gemm<true, true, 128, 4096, 1024, 2, 75 * 32, 1>
        <<<75 * 32, 256, 0, stream>>>((const void*)xb, W1, b1, (void*)h);
  } else {
    expert_gemm<false, true, 128, 4096, 1024, 2, 75 * 32, 1>
        <<<75 * 32, 256, 0, stream>>>((const void*)x, W1, b1, (void*)h);
  }

  // GEMM2: out = h @ W2^T + b2, 128x128 tiles, split-K KS=2 (K-chunk 2048, NT=64),
  // atomic fp32 accumulate, bias/2 folded per chunk. 75 m-tiles x 8 n-tiles x 2 chunks.
  expert_gemm<true, false, 128, 1024, 4096, 0, 2 * 75 * 8, 2>
      <<<2 * 75 * 8, 256, 0, stream>>>((const void*)h, W2, b2, (void*)out);
}